// Round 13
// baseline (154.719 us; speedup 1.0000x reference)
//
#include <hip/hip_runtime.h>
#include <cstdint>
#include <cstddef>

#define B_ 16
#define C_ 256
#define HW_ 9216
#define S_ 128
#define N_ 64
#define LT_ 144         // number of 64-wide l tiles

typedef __attribute__((ext_vector_type(8))) short bf16x8;
typedef __attribute__((ext_vector_type(4))) float f32x4;
typedef __attribute__((ext_vector_type(8))) unsigned short u16x8;

__device__ __forceinline__ unsigned short f2bf(float f) {
    unsigned int u = __builtin_bit_cast(unsigned int, f);
    u += 0x7fffu + ((u >> 16) & 1u);   // RNE; inputs are finite
    return (unsigned short)(u >> 16);
}
__device__ __forceinline__ float bf2f(unsigned short u) {
    unsigned int x = ((unsigned int)u) << 16;
    return __builtin_bit_cast(float, x);
}

// ---------------------------------------------------------------------------
// K0 (fused prep): blocks 0..255 -> Wcf fragment-ordered weights + BN folds;
// blocks 256..543 -> bf16 GCN/fc2 weights.
// ---------------------------------------------------------------------------
__global__ void k0_prep(
    const float* __restrict__ w_s, const float* __restrict__ w_p, const float* __restrict__ w_r,
    const float* __restrict__ b_s, const float* __restrict__ g_s, const float* __restrict__ bb_s,
    const float* __restrict__ m_s, const float* __restrict__ v_s,
    const float* __restrict__ b_p, const float* __restrict__ g_p, const float* __restrict__ bb_p,
    const float* __restrict__ m_p, const float* __restrict__ v_p,
    const float* __restrict__ b_r, const float* __restrict__ g_r, const float* __restrict__ bb_r,
    const float* __restrict__ m_r, const float* __restrict__ v_r,
    const float* __restrict__ og, const float* __restrict__ ob,
    const float* __restrict__ om, const float* __restrict__ ov,
    const float* __restrict__ g1w1, const float* __restrict__ g1w2,
    const float* __restrict__ g2w1, const float* __restrict__ g2w2,
    const float* __restrict__ fc2w,
    unsigned short* __restrict__ Wcf, float* __restrict__ pscale, float* __restrict__ pbeta,
    float* __restrict__ oscale, float* __restrict__ obeta,
    unsigned short* __restrict__ wbf)
{
    if (blockIdx.x >= 256) {       // GCN/fc2 weight bf16-ify
        const int gid = (blockIdx.x - 256) * 256 + threadIdx.x;   // 0..73727
        if (gid < 73728) {
            float v;
            if (gid < 4096)       v = g1w1[gid];
            else if (gid < 20480) v = g1w2[gid - 4096];
            else if (gid < 24576) v = g2w1[gid - 20480];
            else if (gid < 40960) v = g2w2[gid - 24576];
            else                  v = fc2w[gid - 40960];
            wbf[gid] = f2bf(v);
        }
        return;
    }
    const int gid = blockIdx.x * 256 + threadIdx.x;   // 0..65535
    const int oc = gid >> 8, c = gid & 255;
    const float* wsrc;
    if (oc < 128)      wsrc = w_s + oc * 256;
    else if (oc < 192) wsrc = w_p + (oc - 128) * 256;
    else               wsrc = w_r + (oc - 192) * 256;
    Wcf[(c >> 3) * 2048 + oc * 8 + (c & 7)] = f2bf(wsrc[c]);
    if (gid < 256) {
        int i; const float *bp, *gp, *bbp, *mp, *vp;
        if (gid < 128)      { i = gid;       bp = b_s; gp = g_s; bbp = bb_s; mp = m_s; vp = v_s; }
        else if (gid < 192) { i = gid - 128; bp = b_p; gp = g_p; bbp = bb_p; mp = m_p; vp = v_p; }
        else                { i = gid - 192; bp = b_r; gp = g_r; bbp = bb_r; mp = m_r; vp = v_r; }
        const float sc = gp[i] / sqrtf(vp[i] + 1e-5f);
        pscale[gid] = sc;
        pbeta[gid]  = (bp[i] - mp[i]) * sc + bbp[i];
        const float so = og[gid] / sqrtf(ov[gid] + 1e-5f);
        oscale[gid] = so;
        obeta[gid]  = ob[gid] - om[gid] * so;
    }
}

// ---------------------------------------------------------------------------
// K1 v9: kt-loop GEMM with DEPTH-2 x-load pipeline (loads stay in flight
// across two barriers — T3 counted-depth pattern).  One barrier per kt.
// All-wave P[256][76] epilogue, packed xrt stores, split gram tail.
// ---------------------------------------------------------------------------
__global__ __launch_bounds__(256, 3) void k1_proj(
    const float* __restrict__ x, const unsigned short* __restrict__ Wcf,
    const float* __restrict__ pscale, const float* __restrict__ pbeta,
    unsigned short* __restrict__ xrt, unsigned short* __restrict__ gpb)
{
    __shared__ unsigned short SH[19456];      // 38912 B: dbuf[2][64][72] | P[256][76]
    const int t = threadIdx.x;
    const int lane = t & 63;
    const int w = t >> 6;          // oc quarter
    const int lt = blockIdx.x;
    const int b  = blockIdx.y;
    const int l0 = lt * 64;
    const float* xb = x + (size_t)b * C_ * HW_;
    const int lf = lane & 15;
    const int q4 = lane >> 4;
    const int kg0 = q4 * 8;
    const int r4 = q4 * 4;

    const int lq = t & 15;         // stage l-quad (l = lq*4)
    const int cs = t >> 4;         // stage c-slot
    const int c0 = cs * 4;

    f32x4 acc[4][4] = {};          // [mi = l][ni = oc]
    f32x4 F[2][4];                 // depth-2 staged x loads

    // prologue: issue loads for kt = 0 and kt = 1
    #pragma unroll
    for (int j = 0; j < 4; ++j)
        F[0][j] = *(const f32x4*)(xb + (size_t)(0 * 64 + c0 + j) * HW_ + l0 + lq * 4);
    #pragma unroll
    for (int j = 0; j < 4; ++j)
        F[1][j] = *(const f32x4*)(xb + (size_t)(1 * 64 + c0 + j) * HW_ + l0 + lq * 4);

    for (int kt = 0; kt < 4; ++kt) {
        unsigned short* buf = SH + (kt & 1) * 4608;
        // cvt + 4x4 transpose + stage F[kt&1] -> buf
        #pragma unroll
        for (int r = 0; r < 4; ++r) {
            const int ll = lq * 4 + r;
            ushort4 wv;
            wv.x = f2bf(F[kt & 1][0][r]); wv.y = f2bf(F[kt & 1][1][r]);
            wv.z = f2bf(F[kt & 1][2][r]); wv.w = f2bf(F[kt & 1][3][r]);
            *(ushort4*)&buf[ll * 72 + (c0 ^ ((lq & 7) << 3))] = wv;
        }
        __syncthreads();           // one barrier per kt
        // re-arm the just-freed register set with tile kt+2 (2 periods ahead)
        if (kt < 2) {
            const int k0n = (kt + 2) * 64;
            #pragma unroll
            for (int j = 0; j < 4; ++j)
                F[kt & 1][j] = *(const f32x4*)(xb + (size_t)(k0n + c0 + j) * HW_ + l0 + lq * 4);
        }
        #pragma unroll
        for (int ks = 0; ks < 2; ++ks) {
            const int kg = ks * 32 + kg0;
            bf16x8 al[4], bo[4];
            #pragma unroll
            for (int mi = 0; mi < 4; ++mi) {
                const int rr = mi * 16 + lf;
                al[mi] = *(const bf16x8*)&buf[rr * 72 + (kg ^ (((rr >> 2) & 7) << 3))];
            }
            const int chunk = kt * 8 + ks * 4 + q4;
            #pragma unroll
            for (int ni = 0; ni < 4; ++ni)
                bo[ni] = *(const bf16x8*)(Wcf + (size_t)chunk * 2048 + (w * 64 + ni * 16 + lf) * 8);
            #pragma unroll
            for (int mi = 0; mi < 4; ++mi)
                #pragma unroll
                for (int ni = 0; ni < 4; ++ni)
                    acc[mi][ni] = __builtin_amdgcn_mfma_f32_16x16x32_bf16(al[mi], bo[ni], acc[mi][ni], 0, 0, 0);
        }
    }
    __syncthreads();   // all MFMA LDS reads done; SH becomes P

    // ---- epilogue: BN + relu -> P[256][76] (all waves; stride 76) ----
    #pragma unroll
    for (int ni = 0; ni < 4; ++ni) {
        const int oc = w * 64 + ni * 16 + lf;
        const float sc = pscale[oc];
        const float bt = pbeta[oc];
        #pragma unroll
        for (int mi = 0; mi < 4; ++mi) {
            const int lcol = mi * 16 + r4;
            ushort4 pk;
            #pragma unroll
            for (int r = 0; r < 4; ++r) {
                float y = acc[mi][ni][r] * sc + bt;
                y = y > 0.f ? y : 0.f;
                ((unsigned short*)&pk)[r] = f2bf(y);
            }
            *(ushort4*)&SH[oc * 76 + lcol] = pk;
        }
    }
    __syncthreads();

    // ---- xrt: packed coalesced stores from P rows 192..255 ----
    {
        const int l = t >> 2;                 // 0..63
        const int n0 = (t & 3) * 16;          // 0,16,32,48
        u16x8 v0, v1;
        #pragma unroll
        for (int j = 0; j < 8; ++j) v0[j] = SH[(192 + n0 + j) * 76 + l];
        #pragma unroll
        for (int j = 0; j < 8; ++j) v1[j] = SH[(192 + n0 + 8 + j) * 76 + l];
        unsigned short* dst = xrt + ((size_t)b * HW_ + l0 + l) * 64 + n0;
        *(u16x8*)dst = v0;
        *(u16x8*)(dst + 8) = v1;
    }

    // ---- FUSED GRAM TAIL: D[n][s], two n-halves of [2][2] ----
    {
        unsigned short* gp = gpb + (size_t)(lt * 16 + b) * (S_ * N_);
        #pragma unroll
        for (int half = 0; half < 2; ++half) {
            f32x4 acc2[2][2] = {};     // [mi = n pair][ni = s pair]
            #pragma unroll
            for (int ks = 0; ks < 2; ++ks) {
                const int kg = ks * 32 + kg0;
                bf16x8 an[2], bs_[2];
                #pragma unroll
                for (int mi = 0; mi < 2; ++mi)
                    an[mi] = *(const bf16x8*)&SH[(128 + half * 32 + mi * 16 + lf) * 76 + kg];
                #pragma unroll
                for (int ni = 0; ni < 2; ++ni)
                    bs_[ni] = *(const bf16x8*)&SH[(w * 32 + ni * 16 + lf) * 76 + kg];
                #pragma unroll
                for (int mi = 0; mi < 2; ++mi)
                    #pragma unroll
                    for (int ni = 0; ni < 2; ++ni)
                        acc2[mi][ni] = __builtin_amdgcn_mfma_f32_16x16x32_bf16(an[mi], bs_[ni], acc2[mi][ni], 0, 0, 0);
            }
            #pragma unroll
            for (int ni = 0; ni < 2; ++ni) {
                const int s = w * 32 + ni * 16 + lf;
                #pragma unroll
                for (int mi = 0; mi < 2; ++mi) {
                    ushort4 pk;
                    #pragma unroll
                    for (int r = 0; r < 4; ++r)
                        ((unsigned short*)&pk)[r] = f2bf(acc2[mi][ni][r]);
                    *(ushort4*)&gp[s * 64 + half * 32 + mi * 16 + r4] = pk;
                }
            }
        }
    }
}

// ---------------------------------------------------------------------------
// KRED: gred[b][s*64+n] = (sum_lt gpb[lt][b][s*64+n]) / HW  (fp32 accum)
// ---------------------------------------------------------------------------
__global__ __launch_bounds__(256) void kred(
    const unsigned short* __restrict__ gpb, unsigned short* __restrict__ gred)
{
    const int id = blockIdx.x * 256 + threadIdx.x;    // 0..16383 u16x8 units
    float s[8] = {};
    const unsigned short* p = gpb + (size_t)id * 8;
    #pragma unroll 8
    for (int lt = 0; lt < LT_; ++lt) {
        const u16x8 v = *(const u16x8*)(p + (size_t)lt * 16 * (S_ * N_));
        #pragma unroll
        for (int j = 0; j < 8; ++j) s[j] += bf2f(v[j]);
    }
    const float inv = 1.0f / (float)HW_;
    u16x8 h;
    #pragma unroll
    for (int j = 0; j < 8; ++j) h[j] = f2bf(s[j] * inv);
    *(u16x8*)&gred[(size_t)id * 8] = h;
}

// ---------------------------------------------------------------------------
// K_gcn (MFMA): per batch, 4 waves; loads gred bf16 directly.
// ---------------------------------------------------------------------------
__global__ __launch_bounds__(256) void k_gcn(
    const unsigned short* __restrict__ gred, const unsigned short* __restrict__ wbf,
    const float* __restrict__ b1a, const float* __restrict__ b1b,
    unsigned short* __restrict__ hc)
{
    __shared__ unsigned short G[128 * 72];
    __shared__ unsigned short HT[64 * 136];
    __shared__ unsigned short T2[64 * 136];
    const int b = blockIdx.x;
    const int t = threadIdx.x;
    const int lane = t & 63;
    const int w = t >> 6;
    const int lf = lane & 15;
    const int kg0 = (lane >> 4) * 8;
    const int r4 = (lane >> 4) * 4;

    const unsigned short* w1a = wbf;
    const unsigned short* w2a = wbf + 4096;
    const unsigned short* w1b = wbf + 20480;
    const unsigned short* w2b = wbf + 24576;
    const unsigned short* fc2 = wbf + 40960;

    #pragma unroll
    for (int i = 0; i < 4; ++i) {
        const int chunk = t + i * 256;        // 0..1023, 8 ush each
        const u16x8 v = *(const u16x8*)(gred + (size_t)b * (S_ * N_) + chunk * 8);
        const int s = chunk >> 3, n = (chunk & 7) * 8;
        *(u16x8*)&G[s * 72 + n] = v;
    }
    __syncthreads();

    for (int pass = 0; pass < 2; ++pass) {
        const unsigned short* w1 = pass ? w1b : w1a;
        const unsigned short* w2 = pass ? w2b : w2a;
        const float* b1 = pass ? b1b : b1a;

        {   // node mix: Y[s,m]=sum_n G[s,n]*w1[m,n]; h=leaky(Y+b1+G) -> HT[m][s]
            f32x4 acc[2][4] = {};
            #pragma unroll
            for (int ks = 0; ks < 2; ++ks) {
                const int kg = ks * 32 + kg0;
                bf16x8 a[2], bv[4];
                #pragma unroll
                for (int mi = 0; mi < 2; ++mi)
                    a[mi] = *(const bf16x8*)&G[(w * 32 + mi * 16 + lf) * 72 + kg];
                #pragma unroll
                for (int ni = 0; ni < 4; ++ni)
                    bv[ni] = *(const bf16x8*)(w1 + (ni * 16 + lf) * 64 + kg);
                #pragma unroll
                for (int mi = 0; mi < 2; ++mi)
                    #pragma unroll
                    for (int ni = 0; ni < 4; ++ni)
                        acc[mi][ni] = __builtin_amdgcn_mfma_f32_16x16x32_bf16(a[mi], bv[ni], acc[mi][ni], 0, 0, 0);
            }
            #pragma unroll
            for (int mi = 0; mi < 2; ++mi) {
                const int s0 = w * 32 + mi * 16 + r4;
                #pragma unroll
                for (int ni = 0; ni < 4; ++ni) {
                    const int m = ni * 16 + lf;
                    const float bm = b1[m];
                    ushort4 pk;
                    #pragma unroll
                    for (int r = 0; r < 4; ++r) {
                        float v = acc[mi][ni][r] + bm + bf2f(G[(s0 + r) * 72 + m]);
                        v = v > 0.f ? v : 0.2f * v;
                        ((unsigned short*)&pk)[r] = f2bf(v);
                    }
                    *(ushort4*)&HT[m * 136 + s0] = pk;
                }
            }
        }
        __syncthreads();

        {   // state mix: Z[t,m] = sum_s w2[t,s]*h[s,m]
            f32x4 acc[2][4] = {};
            #pragma unroll
            for (int ks = 0; ks < 4; ++ks) {
                const int kg = ks * 32 + kg0;
                bf16x8 a[2], bv[4];
                #pragma unroll
                for (int mi = 0; mi < 2; ++mi)
                    a[mi] = *(const bf16x8*)(w2 + (w * 32 + mi * 16 + lf) * 128 + kg);
                #pragma unroll
                for (int ni = 0; ni < 4; ++ni)
                    bv[ni] = *(const bf16x8*)&HT[(ni * 16 + lf) * 136 + kg];
                #pragma unroll
                for (int mi = 0; mi < 2; ++mi)
                    #pragma unroll
                    for (int ni = 0; ni < 4; ++ni)
                        acc[mi][ni] = __builtin_amdgcn_mfma_f32_16x16x32_bf16(a[mi], bv[ni], acc[mi][ni], 0, 0, 0);
            }
            if (pass == 0) {
                #pragma unroll
                for (int mi = 0; mi < 2; ++mi) {
                    const int t0 = w * 32 + mi * 16 + r4;
                    #pragma unroll
                    for (int ni = 0; ni < 4; ++ni) {
                        const int m = ni * 16 + lf;
                        #pragma unroll
                        for (int r = 0; r < 4; ++r)
                            G[(t0 + r) * 72 + m] = f2bf(acc[mi][ni][r]);
                    }
                }
            } else {
                #pragma unroll
                for (int mi = 0; mi < 2; ++mi) {
                    const int t0 = w * 32 + mi * 16 + r4;
                    #pragma unroll
                    for (int ni = 0; ni < 4; ++ni) {
                        const int m = ni * 16 + lf;
                        ushort4 pk;
                        #pragma unroll
                        for (int r = 0; r < 4; ++r)
                            ((unsigned short*)&pk)[r] = f2bf(acc[mi][ni][r]);
                        *(ushort4*)&T2[m * 136 + t0] = pk;
                    }
                }
            }
        }
        __syncthreads();
    }

    {   // fc2 fold: hc[c,n] = sum_t fc2[c,t]*g2[t,n]
        f32x4 acc[4][4] = {};
        #pragma unroll
        for (int ks = 0; ks < 4; ++ks) {
            const int kg = ks * 32 + kg0;
            bf16x8 a[4], bv[4];
            #pragma unroll
            for (int mi = 0; mi < 4; ++mi)
                a[mi] = *(const bf16x8*)(fc2 + (w * 64 + mi * 16 + lf) * 128 + kg);
            #pragma unroll
            for (int ni = 0; ni < 4; ++ni)
                bv[ni] = *(const bf16x8*)&T2[(ni * 16 + lf) * 136 + kg];
            #pragma unroll
            for (int mi = 0; mi < 4; ++mi)
                #pragma unroll
                for (int ni = 0; ni < 4; ++ni)
                    acc[mi][ni] = __builtin_amdgcn_mfma_f32_16x16x32_bf16(a[mi], bv[ni], acc[mi][ni], 0, 0, 0);
        }
        #pragma unroll
        for (int mi = 0; mi < 4; ++mi) {
            const int c0 = w * 64 + mi * 16 + r4;
            #pragma unroll
            for (int ni = 0; ni < 4; ++ni) {
                const int n = ni * 16 + lf;
                #pragma unroll
                for (int r = 0; r < 4; ++r)
                    hc[((size_t)b * 256 + c0 + r) * 64 + n] = f2bf(acc[mi][ni][r]);
            }
        }
    }
}

// ---------------------------------------------------------------------------
// K3 (no-LDS + x prefetch): out = x + oscale*(hc·xr) + obeta
// ---------------------------------------------------------------------------
__global__ __launch_bounds__(256) void k3_out(
    const float* __restrict__ x, const unsigned short* __restrict__ hc,
    const unsigned short* __restrict__ xrt,
    const float* __restrict__ oscale, const float* __restrict__ obeta,
    float* __restrict__ out)
{
    const int t = threadIdx.x;
    const int lane = t & 63;
    const int w = t >> 6;
    const int wr = w >> 1, wc = w & 1;
    const int l0 = blockIdx.x * 128;
    const int moff = blockIdx.y * 128;
    const int b = blockIdx.z;
    const int lf = lane & 15;
    const int q4 = lane >> 4;
    const int kg0 = q4 * 8;
    const int r4 = q4 * 4;

    const unsigned short* hb = hc + (size_t)b * 256 * 64 + (size_t)(moff + wr * 64) * 64;
    const unsigned short* xrb = xrt + ((size_t)b * HW_ + l0 + wc * 64) * 64;

    f32x4 xpre[8];
    #pragma unroll
    for (int p = 0; p < 8; ++p) {
        const int ni = p >> 2, mi = p & 3;
        const int c = moff + wr * 64 + ni * 16 + lf;
        const int l = l0 + wc * 64 + mi * 16 + r4;
        xpre[p] = *(const f32x4*)(x + ((size_t)b * 256 + c) * HW_ + l);
    }

    f32x4 acc[4][4] = {};   // [mi = l][ni = c]
    #pragma unroll
    for (int ks = 0; ks < 2; ++ks) {
        const int kg = ks * 32 + kg0;
        bf16x8 al[4], bc[4];
        #pragma unroll
        for (int mi = 0; mi < 4; ++mi)
            al[mi] = *(const bf16x8*)(xrb + (size_t)(mi * 16 + lf) * 64 + kg);
        #pragma unroll
        for (int ni = 0; ni < 4; ++ni)
            bc[ni] = *(const bf16x8*)(hb + (size_t)(ni * 16 + lf) * 64 + kg);
        #pragma unroll
        for (int mi = 0; mi < 4; ++mi)
            #pragma unroll
            for (int ni = 0; ni < 4; ++ni)
                acc[mi][ni] = __builtin_amdgcn_mfma_f32_16x16x32_bf16(al[mi], bc[ni], acc[mi][ni], 0, 0, 0);
    }
    #pragma unroll
    for (int ni = 0; ni < 4; ++ni) {
        const int c = moff + wr * 64 + ni * 16 + lf;
        const float sc = oscale[c];
        const float bt = obeta[c];
        const size_t rowb = ((size_t)b * 256 + c) * HW_;
        #pragma unroll
        for (int mi = 0; mi < 4; ++mi) {
            const int l = l0 + wc * 64 + mi * 16 + r4;
            const f32x4 xv = (ni < 2) ? xpre[ni * 4 + mi]
                                      : *(const f32x4*)(x + rowb + l);
            f32x4 o;
            #pragma unroll
            for (int r = 0; r < 4; ++r)
                o[r] = xv[r] + acc[mi][ni][r] * sc + bt;
            *(f32x4*)(out + rowb + l) = o;
        }
    }
}

// ---------------------------------------------------------------------------
extern "C" void kernel_launch(void* const* d_in, const int* in_sizes, int n_in,
                              void* d_out, int out_size, void* d_ws, size_t ws_size,
                              hipStream_t stream) {
    (void)in_sizes; (void)n_in; (void)out_size;
    const float* x     = (const float*)d_in[0];
    const float* w_s   = (const float*)d_in[1];
    const float* b_s   = (const float*)d_in[2];
    const float* g_s   = (const float*)d_in[3];
    const float* bb_s  = (const float*)d_in[4];
    const float* m_s   = (const float*)d_in[5];
    const float* v_s   = (const float*)d_in[6];
    const float* w_p   = (const float*)d_in[7];
    const float* b_p   = (const float*)d_in[8];
    const float* g_p   = (const float*)d_in[9];
    const float* bb_p  = (const float*)d_in[10];
    const float* m_p   = (const float*)d_in[11];
    const float* v_p   = (const float*)d_in[12];
    const float* w_r   = (const float*)d_in[13];
    const float* b_r   = (const float*)d_in[14];
    const float* g_r   = (const float*)d_in[15];
    const float* bb_r  = (const float*)d_in[16];
    const float* m_r   = (const float*)d_in[17];
    const float* v_r   = (const float*)d_in[18];
    const float* g1w1  = (const float*)d_in[19];
    const float* g1b1  = (const float*)d_in[20];
    const float* g1w2  = (const float*)d_in[21];
    const float* g2w1  = (const float*)d_in[22];
    const float* g2b1  = (const float*)d_in[23];
    const float* g2w2  = (const float*)d_in[24];
    const float* fc2w  = (const float*)d_in[25];
    const float* bn_og = (const float*)d_in[26];
    const float* bn_ob = (const float*)d_in[27];
    const float* bn_om = (const float*)d_in[28];
    const float* bn_ov = (const float*)d_in[29];

    char* ws = (char*)d_ws;
    unsigned short* Wcf = (unsigned short*)(ws + 0);         // 131072 B
    float* pscale = (float*)(ws + 131072);
    float* pbeta  = (float*)(ws + 132096);
    float* oscale = (float*)(ws + 133120);
    float* obeta  = (float*)(ws + 134144);
    unsigned short* wbf = (unsigned short*)(ws + 135168);    // 147456 B
    const size_t o_fix = 135168 + 147456;                    // 282624
    const size_t sz_xrt = (size_t)B_ * HW_ * 64 * 2;         // 18,874,368
    const size_t sz_gr  = (size_t)B_ * S_ * N_ * 2;          //    262,144
    const size_t sz_hc  = (size_t)B_ * 256 * 64 * 2;         //    524,288
    const size_t sz_gpb = (size_t)LT_ * B_ * S_ * N_ * 2;    // 37,748,736
    const size_t need_full = o_fix + sz_xrt + sz_gr + sz_hc + sz_gpb;

    unsigned short* xrt  = (unsigned short*)(ws + o_fix);
    unsigned short* gred = (unsigned short*)(ws + o_fix + sz_xrt);
    unsigned short* hc   = (unsigned short*)(ws + o_fix + sz_xrt + sz_gr);
    unsigned short* gpb;
    if (ws_size >= need_full)
        gpb = (unsigned short*)(ws + o_fix + sz_xrt + sz_gr + sz_hc);
    else  // fall back: gpb in d_out (fully consumed by kred before k3 writes out)
        gpb = (unsigned short*)d_out;

    k0_prep<<<544, 256, 0, stream>>>(
        w_s, w_p, w_r,
        b_s, g_s, bb_s, m_s, v_s,
        b_p, g_p, bb_p, m_p, v_p,
        b_r, g_r, bb_r, m_r, v_r,
        bn_og, bn_ob, bn_om, bn_ov,
        g1w1, g1w2, g2w1, g2w2, fc2w,
        Wcf, pscale, pbeta, oscale, obeta, wbf);

    k1_proj<<<dim3(LT_, B_), 256, 0, stream>>>(x, Wcf, pscale, pbeta, xrt, gpb);

    kred<<<64, 256, 0, stream>>>(gpb, gred);

    k_gcn<<<16, 256, 0, stream>>>(gred, wbf, g1b1, g2b1, hc);

    k3_out<<<dim3(72, 2, 16), 256, 0, stream>>>(x, hc, xrt, oscale, obeta, (float*)d_out);
}

// Round 14
// 150.687 us; speedup vs baseline: 1.0268x; 1.0268x over previous
//
#include <hip/hip_runtime.h>
#include <cstdint>
#include <cstddef>

#define B_ 16
#define C_ 256
#define HW_ 9216
#define S_ 128
#define N_ 64
#define LT_ 144         // number of 64-wide l tiles

typedef __attribute__((ext_vector_type(8))) short bf16x8;
typedef __attribute__((ext_vector_type(4))) float f32x4;
typedef __attribute__((ext_vector_type(8))) unsigned short u16x8;

__device__ __forceinline__ unsigned short f2bf(float f) {
    unsigned int u = __builtin_bit_cast(unsigned int, f);
    u += 0x7fffu + ((u >> 16) & 1u);   // RNE; inputs are finite
    return (unsigned short)(u >> 16);
}
__device__ __forceinline__ float bf2f(unsigned short u) {
    unsigned int x = ((unsigned int)u) << 16;
    return __builtin_bit_cast(float, x);
}

// ---------------------------------------------------------------------------
// K0 (fused prep): blocks 0..255 -> Wcf fragment-ordered weights + BN folds;
// blocks 256..543 -> bf16 GCN/fc2 weights.
// ---------------------------------------------------------------------------
__global__ void k0_prep(
    const float* __restrict__ w_s, const float* __restrict__ w_p, const float* __restrict__ w_r,
    const float* __restrict__ b_s, const float* __restrict__ g_s, const float* __restrict__ bb_s,
    const float* __restrict__ m_s, const float* __restrict__ v_s,
    const float* __restrict__ b_p, const float* __restrict__ g_p, const float* __restrict__ bb_p,
    const float* __restrict__ m_p, const float* __restrict__ v_p,
    const float* __restrict__ b_r, const float* __restrict__ g_r, const float* __restrict__ bb_r,
    const float* __restrict__ m_r, const float* __restrict__ v_r,
    const float* __restrict__ og, const float* __restrict__ ob,
    const float* __restrict__ om, const float* __restrict__ ov,
    const float* __restrict__ g1w1, const float* __restrict__ g1w2,
    const float* __restrict__ g2w1, const float* __restrict__ g2w2,
    const float* __restrict__ fc2w,
    unsigned short* __restrict__ Wcf, float* __restrict__ pscale, float* __restrict__ pbeta,
    float* __restrict__ oscale, float* __restrict__ obeta,
    unsigned short* __restrict__ wbf)
{
    if (blockIdx.x >= 256) {       // GCN/fc2 weight bf16-ify
        const int gid = (blockIdx.x - 256) * 256 + threadIdx.x;   // 0..73727
        if (gid < 73728) {
            float v;
            if (gid < 4096)       v = g1w1[gid];
            else if (gid < 20480) v = g1w2[gid - 4096];
            else if (gid < 24576) v = g2w1[gid - 20480];
            else if (gid < 40960) v = g2w2[gid - 24576];
            else                  v = fc2w[gid - 40960];
            wbf[gid] = f2bf(v);
        }
        return;
    }
    const int gid = blockIdx.x * 256 + threadIdx.x;   // 0..65535
    const int oc = gid >> 8, c = gid & 255;
    const float* wsrc;
    if (oc < 128)      wsrc = w_s + oc * 256;
    else if (oc < 192) wsrc = w_p + (oc - 128) * 256;
    else               wsrc = w_r + (oc - 192) * 256;
    Wcf[(c >> 3) * 2048 + oc * 8 + (c & 7)] = f2bf(wsrc[c]);
    if (gid < 256) {
        int i; const float *bp, *gp, *bbp, *mp, *vp;
        if (gid < 128)      { i = gid;       bp = b_s; gp = g_s; bbp = bb_s; mp = m_s; vp = v_s; }
        else if (gid < 192) { i = gid - 128; bp = b_p; gp = g_p; bbp = bb_p; mp = m_p; vp = v_p; }
        else                { i = gid - 192; bp = b_r; gp = g_r; bbp = bb_r; mp = m_r; vp = v_r; }
        const float sc = gp[i] / sqrtf(vp[i] + 1e-5f);
        pscale[gid] = sc;
        pbeta[gid]  = (bp[i] - mp[i]) * sc + bbp[i];
        const float so = og[gid] / sqrtf(ov[gid] + 1e-5f);
        oscale[gid] = so;
        obeta[gid]  = ob[gid] - om[gid] * so;
    }
}

// ---------------------------------------------------------------------------
// K1 v10: kt-loop GEMM; x-loads depth-2 (F) AND Wcf fragments register-
// resident one kt ahead (bo) — next kt's weight loads are issued at the END
// of the current MFMA block so they cross the barrier in flight.  Zero
// exposed global latency in the k-loop.  One barrier per kt.
// ---------------------------------------------------------------------------
__global__ __launch_bounds__(256, 3) void k1_proj(
    const float* __restrict__ x, const unsigned short* __restrict__ Wcf,
    const float* __restrict__ pscale, const float* __restrict__ pbeta,
    unsigned short* __restrict__ xrt, unsigned short* __restrict__ gpb)
{
    __shared__ unsigned short SH[19456];      // 38912 B: dbuf[2][64][72] | P[256][76]
    const int t = threadIdx.x;
    const int lane = t & 63;
    const int w = t >> 6;          // oc quarter
    const int lt = blockIdx.x;
    const int b  = blockIdx.y;
    const int l0 = lt * 64;
    const float* xb = x + (size_t)b * C_ * HW_;
    const int lf = lane & 15;
    const int q4 = lane >> 4;
    const int kg0 = q4 * 8;
    const int r4 = q4 * 4;

    const int lq = t & 15;         // stage l-quad (l = lq*4)
    const int cs = t >> 4;         // stage c-slot
    const int c0 = cs * 4;

    // per-thread Wcf fragment base (chunk stride 2048 elements)
    const unsigned short* wbase = Wcf + (size_t)q4 * 2048 + (w * 64 + lf) * 8;

    f32x4 acc[4][4] = {};          // [mi = l][ni = oc]
    f32x4 F[2][4];                 // depth-2 staged x loads
    bf16x8 bo[2][4];               // current kt's Wcf fragments (prefetched)

    // prologue: x loads for kt=0,1 and Wcf fragments for kt=0
    #pragma unroll
    for (int j = 0; j < 4; ++j)
        F[0][j] = *(const f32x4*)(xb + (size_t)(c0 + j) * HW_ + l0 + lq * 4);
    #pragma unroll
    for (int j = 0; j < 4; ++j)
        F[1][j] = *(const f32x4*)(xb + (size_t)(64 + c0 + j) * HW_ + l0 + lq * 4);
    #pragma unroll
    for (int ks = 0; ks < 2; ++ks)
        #pragma unroll
        for (int ni = 0; ni < 4; ++ni)
            bo[ks][ni] = *(const bf16x8*)(wbase + (size_t)(ks * 4) * 2048 + ni * 128);

    for (int kt = 0; kt < 4; ++kt) {
        unsigned short* buf = SH + (kt & 1) * 4608;
        // cvt + 4x4 transpose + stage F[kt&1] -> buf
        #pragma unroll
        for (int r = 0; r < 4; ++r) {
            const int ll = lq * 4 + r;
            ushort4 wv;
            wv.x = f2bf(F[kt & 1][0][r]); wv.y = f2bf(F[kt & 1][1][r]);
            wv.z = f2bf(F[kt & 1][2][r]); wv.w = f2bf(F[kt & 1][3][r]);
            *(ushort4*)&buf[ll * 72 + (c0 ^ ((lq & 7) << 3))] = wv;
        }
        __syncthreads();           // one barrier per kt
        // re-arm x registers with tile kt+2 (2 periods ahead)
        if (kt < 2) {
            const int k0n = (kt + 2) * 64;
            #pragma unroll
            for (int j = 0; j < 4; ++j)
                F[kt & 1][j] = *(const f32x4*)(xb + (size_t)(k0n + c0 + j) * HW_ + l0 + lq * 4);
        }
        // MFMA using the PRE-LOADED bo fragments (no post-barrier global wait)
        #pragma unroll
        for (int ks = 0; ks < 2; ++ks) {
            const int kg = ks * 32 + kg0;
            bf16x8 al[4];
            #pragma unroll
            for (int mi = 0; mi < 4; ++mi) {
                const int rr = mi * 16 + lf;
                al[mi] = *(const bf16x8*)&buf[rr * 72 + (kg ^ (((rr >> 2) & 7) << 3))];
            }
            #pragma unroll
            for (int mi = 0; mi < 4; ++mi)
                #pragma unroll
                for (int ni = 0; ni < 4; ++ni)
                    acc[mi][ni] = __builtin_amdgcn_mfma_f32_16x16x32_bf16(al[mi], bo[ks][ni], acc[mi][ni], 0, 0, 0);
        }
        // prefetch next kt's Wcf fragments (in flight across next barrier)
        if (kt < 3) {
            const unsigned short* wkt = wbase + (size_t)((kt + 1) * 8) * 2048;
            #pragma unroll
            for (int ks = 0; ks < 2; ++ks)
                #pragma unroll
                for (int ni = 0; ni < 4; ++ni)
                    bo[ks][ni] = *(const bf16x8*)(wkt + (size_t)(ks * 4) * 2048 + ni * 128);
        }
    }
    __syncthreads();   // all MFMA LDS reads done; SH becomes P

    // ---- epilogue: BN + relu -> P[256][76] (all waves; stride 76) ----
    #pragma unroll
    for (int ni = 0; ni < 4; ++ni) {
        const int oc = w * 64 + ni * 16 + lf;
        const float sc = pscale[oc];
        const float bt = pbeta[oc];
        #pragma unroll
        for (int mi = 0; mi < 4; ++mi) {
            const int lcol = mi * 16 + r4;
            ushort4 pk;
            #pragma unroll
            for (int r = 0; r < 4; ++r) {
                float y = acc[mi][ni][r] * sc + bt;
                y = y > 0.f ? y : 0.f;
                ((unsigned short*)&pk)[r] = f2bf(y);
            }
            *(ushort4*)&SH[oc * 76 + lcol] = pk;
        }
    }
    __syncthreads();

    // ---- xrt: packed coalesced stores from P rows 192..255 ----
    {
        const int l = t >> 2;                 // 0..63
        const int n0 = (t & 3) * 16;          // 0,16,32,48
        u16x8 v0, v1;
        #pragma unroll
        for (int j = 0; j < 8; ++j) v0[j] = SH[(192 + n0 + j) * 76 + l];
        #pragma unroll
        for (int j = 0; j < 8; ++j) v1[j] = SH[(192 + n0 + 8 + j) * 76 + l];
        unsigned short* dst = xrt + ((size_t)b * HW_ + l0 + l) * 64 + n0;
        *(u16x8*)dst = v0;
        *(u16x8*)(dst + 8) = v1;
    }

    // ---- FUSED GRAM TAIL: D[n][s], two n-halves of [2][2] ----
    {
        unsigned short* gp = gpb + (size_t)(lt * 16 + b) * (S_ * N_);
        #pragma unroll
        for (int half = 0; half < 2; ++half) {
            f32x4 acc2[2][2] = {};     // [mi = n pair][ni = s pair]
            #pragma unroll
            for (int ks = 0; ks < 2; ++ks) {
                const int kg = ks * 32 + kg0;
                bf16x8 an[2], bs_[2];
                #pragma unroll
                for (int mi = 0; mi < 2; ++mi)
                    an[mi] = *(const bf16x8*)&SH[(128 + half * 32 + mi * 16 + lf) * 76 + kg];
                #pragma unroll
                for (int ni = 0; ni < 2; ++ni)
                    bs_[ni] = *(const bf16x8*)&SH[(w * 32 + ni * 16 + lf) * 76 + kg];
                #pragma unroll
                for (int mi = 0; mi < 2; ++mi)
                    #pragma unroll
                    for (int ni = 0; ni < 2; ++ni)
                        acc2[mi][ni] = __builtin_amdgcn_mfma_f32_16x16x32_bf16(an[mi], bs_[ni], acc2[mi][ni], 0, 0, 0);
            }
            #pragma unroll
            for (int ni = 0; ni < 2; ++ni) {
                const int s = w * 32 + ni * 16 + lf;
                #pragma unroll
                for (int mi = 0; mi < 2; ++mi) {
                    ushort4 pk;
                    #pragma unroll
                    for (int r = 0; r < 4; ++r)
                        ((unsigned short*)&pk)[r] = f2bf(acc2[mi][ni][r]);
                    *(ushort4*)&gp[s * 64 + half * 32 + mi * 16 + r4] = pk;
                }
            }
        }
    }
}

// ---------------------------------------------------------------------------
// KRED: gred[b][s*64+n] = (sum_lt gpb[lt][b][s*64+n]) / HW  (fp32 accum)
// ---------------------------------------------------------------------------
__global__ __launch_bounds__(256) void kred(
    const unsigned short* __restrict__ gpb, unsigned short* __restrict__ gred)
{
    const int id = blockIdx.x * 256 + threadIdx.x;    // 0..16383 u16x8 units
    float s[8] = {};
    const unsigned short* p = gpb + (size_t)id * 8;
    #pragma unroll 8
    for (int lt = 0; lt < LT_; ++lt) {
        const u16x8 v = *(const u16x8*)(p + (size_t)lt * 16 * (S_ * N_));
        #pragma unroll
        for (int j = 0; j < 8; ++j) s[j] += bf2f(v[j]);
    }
    const float inv = 1.0f / (float)HW_;
    u16x8 h;
    #pragma unroll
    for (int j = 0; j < 8; ++j) h[j] = f2bf(s[j] * inv);
    *(u16x8*)&gred[(size_t)id * 8] = h;
}

// ---------------------------------------------------------------------------
// K_gcn (MFMA): per batch, 4 waves; loads gred bf16 directly.
// ---------------------------------------------------------------------------
__global__ __launch_bounds__(256) void k_gcn(
    const unsigned short* __restrict__ gred, const unsigned short* __restrict__ wbf,
    const float* __restrict__ b1a, const float* __restrict__ b1b,
    unsigned short* __restrict__ hc)
{
    __shared__ unsigned short G[128 * 72];
    __shared__ unsigned short HT[64 * 136];
    __shared__ unsigned short T2[64 * 136];
    const int b = blockIdx.x;
    const int t = threadIdx.x;
    const int lane = t & 63;
    const int w = t >> 6;
    const int lf = lane & 15;
    const int kg0 = (lane >> 4) * 8;
    const int r4 = (lane >> 4) * 4;

    const unsigned short* w1a = wbf;
    const unsigned short* w2a = wbf + 4096;
    const unsigned short* w1b = wbf + 20480;
    const unsigned short* w2b = wbf + 24576;
    const unsigned short* fc2 = wbf + 40960;

    #pragma unroll
    for (int i = 0; i < 4; ++i) {
        const int chunk = t + i * 256;        // 0..1023, 8 ush each
        const u16x8 v = *(const u16x8*)(gred + (size_t)b * (S_ * N_) + chunk * 8);
        const int s = chunk >> 3, n = (chunk & 7) * 8;
        *(u16x8*)&G[s * 72 + n] = v;
    }
    __syncthreads();

    for (int pass = 0; pass < 2; ++pass) {
        const unsigned short* w1 = pass ? w1b : w1a;
        const unsigned short* w2 = pass ? w2b : w2a;
        const float* b1 = pass ? b1b : b1a;

        {   // node mix: Y[s,m]=sum_n G[s,n]*w1[m,n]; h=leaky(Y+b1+G) -> HT[m][s]
            f32x4 acc[2][4] = {};
            #pragma unroll
            for (int ks = 0; ks < 2; ++ks) {
                const int kg = ks * 32 + kg0;
                bf16x8 a[2], bv[4];
                #pragma unroll
                for (int mi = 0; mi < 2; ++mi)
                    a[mi] = *(const bf16x8*)&G[(w * 32 + mi * 16 + lf) * 72 + kg];
                #pragma unroll
                for (int ni = 0; ni < 4; ++ni)
                    bv[ni] = *(const bf16x8*)(w1 + (ni * 16 + lf) * 64 + kg);
                #pragma unroll
                for (int mi = 0; mi < 2; ++mi)
                    #pragma unroll
                    for (int ni = 0; ni < 4; ++ni)
                        acc[mi][ni] = __builtin_amdgcn_mfma_f32_16x16x32_bf16(a[mi], bv[ni], acc[mi][ni], 0, 0, 0);
            }
            #pragma unroll
            for (int mi = 0; mi < 2; ++mi) {
                const int s0 = w * 32 + mi * 16 + r4;
                #pragma unroll
                for (int ni = 0; ni < 4; ++ni) {
                    const int m = ni * 16 + lf;
                    const float bm = b1[m];
                    ushort4 pk;
                    #pragma unroll
                    for (int r = 0; r < 4; ++r) {
                        float v = acc[mi][ni][r] + bm + bf2f(G[(s0 + r) * 72 + m]);
                        v = v > 0.f ? v : 0.2f * v;
                        ((unsigned short*)&pk)[r] = f2bf(v);
                    }
                    *(ushort4*)&HT[m * 136 + s0] = pk;
                }
            }
        }
        __syncthreads();

        {   // state mix: Z[t,m] = sum_s w2[t,s]*h[s,m]
            f32x4 acc[2][4] = {};
            #pragma unroll
            for (int ks = 0; ks < 4; ++ks) {
                const int kg = ks * 32 + kg0;
                bf16x8 a[2], bv[4];
                #pragma unroll
                for (int mi = 0; mi < 2; ++mi)
                    a[mi] = *(const bf16x8*)(w2 + (w * 32 + mi * 16 + lf) * 128 + kg);
                #pragma unroll
                for (int ni = 0; ni < 4; ++ni)
                    bv[ni] = *(const bf16x8*)&HT[(ni * 16 + lf) * 136 + kg];
                #pragma unroll
                for (int mi = 0; mi < 2; ++mi)
                    #pragma unroll
                    for (int ni = 0; ni < 4; ++ni)
                        acc[mi][ni] = __builtin_amdgcn_mfma_f32_16x16x32_bf16(a[mi], bv[ni], acc[mi][ni], 0, 0, 0);
            }
            if (pass == 0) {
                #pragma unroll
                for (int mi = 0; mi < 2; ++mi) {
                    const int t0 = w * 32 + mi * 16 + r4;
                    #pragma unroll
                    for (int ni = 0; ni < 4; ++ni) {
                        const int m = ni * 16 + lf;
                        #pragma unroll
                        for (int r = 0; r < 4; ++r)
                            G[(t0 + r) * 72 + m] = f2bf(acc[mi][ni][r]);
                    }
                }
            } else {
                #pragma unroll
                for (int mi = 0; mi < 2; ++mi) {
                    const int t0 = w * 32 + mi * 16 + r4;
                    #pragma unroll
                    for (int ni = 0; ni < 4; ++ni) {
                        const int m = ni * 16 + lf;
                        ushort4 pk;
                        #pragma unroll
                        for (int r = 0; r < 4; ++r)
                            ((unsigned short*)&pk)[r] = f2bf(acc[mi][ni][r]);
                        *(ushort4*)&T2[m * 136 + t0] = pk;
                    }
                }
            }
        }
        __syncthreads();
    }

    {   // fc2 fold: hc[c,n] = sum_t fc2[c,t]*g2[t,n]
        f32x4 acc[4][4] = {};
        #pragma unroll
        for (int ks = 0; ks < 4; ++ks) {
            const int kg = ks * 32 + kg0;
            bf16x8 a[4], bv[4];
            #pragma unroll
            for (int mi = 0; mi < 4; ++mi)
                a[mi] = *(const bf16x8*)(fc2 + (w * 64 + mi * 16 + lf) * 128 + kg);
            #pragma unroll
            for (int ni = 0; ni < 4; ++ni)
                bv[ni] = *(const bf16x8*)&T2[(ni * 16 + lf) * 136 + kg];
            #pragma unroll
            for (int mi = 0; mi < 4; ++mi)
                #pragma unroll
                for (int ni = 0; ni < 4; ++ni)
                    acc[mi][ni] = __builtin_amdgcn_mfma_f32_16x16x32_bf16(a[mi], bv[ni], acc[mi][ni], 0, 0, 0);
        }
        #pragma unroll
        for (int mi = 0; mi < 4; ++mi) {
            const int c0 = w * 64 + mi * 16 + r4;
            #pragma unroll
            for (int ni = 0; ni < 4; ++ni) {
                const int n = ni * 16 + lf;
                #pragma unroll
                for (int r = 0; r < 4; ++r)
                    hc[((size_t)b * 256 + c0 + r) * 64 + n] = f2bf(acc[mi][ni][r]);
            }
        }
    }
}

// ---------------------------------------------------------------------------
// K3 (no-LDS + x prefetch): out = x + oscale*(hc·xr) + obeta
// ---------------------------------------------------------------------------
__global__ __launch_bounds__(256) void k3_out(
    const float* __restrict__ x, const unsigned short* __restrict__ hc,
    const unsigned short* __restrict__ xrt,
    const float* __restrict__ oscale, const float* __restrict__ obeta,
    float* __restrict__ out)
{
    const int t = threadIdx.x;
    const int lane = t & 63;
    const int w = t >> 6;
    const int wr = w >> 1, wc = w & 1;
    const int l0 = blockIdx.x * 128;
    const int moff = blockIdx.y * 128;
    const int b = blockIdx.z;
    const int lf = lane & 15;
    const int q4 = lane >> 4;
    const int kg0 = q4 * 8;
    const int r4 = q4 * 4;

    const unsigned short* hb = hc + (size_t)b * 256 * 64 + (size_t)(moff + wr * 64) * 64;
    const unsigned short* xrb = xrt + ((size_t)b * HW_ + l0 + wc * 64) * 64;

    f32x4 xpre[8];
    #pragma unroll
    for (int p = 0; p < 8; ++p) {
        const int ni = p >> 2, mi = p & 3;
        const int c = moff + wr * 64 + ni * 16 + lf;
        const int l = l0 + wc * 64 + mi * 16 + r4;
        xpre[p] = *(const f32x4*)(x + ((size_t)b * 256 + c) * HW_ + l);
    }

    f32x4 acc[4][4] = {};   // [mi = l][ni = c]
    #pragma unroll
    for (int ks = 0; ks < 2; ++ks) {
        const int kg = ks * 32 + kg0;
        bf16x8 al[4], bc[4];
        #pragma unroll
        for (int mi = 0; mi < 4; ++mi)
            al[mi] = *(const bf16x8*)(xrb + (size_t)(mi * 16 + lf) * 64 + kg);
        #pragma unroll
        for (int ni = 0; ni < 4; ++ni)
            bc[ni] = *(const bf16x8*)(hb + (size_t)(ni * 16 + lf) * 64 + kg);
        #pragma unroll
        for (int mi = 0; mi < 4; ++mi)
            #pragma unroll
            for (int ni = 0; ni < 4; ++ni)
                acc[mi][ni] = __builtin_amdgcn_mfma_f32_16x16x32_bf16(al[mi], bc[ni], acc[mi][ni], 0, 0, 0);
    }
    #pragma unroll
    for (int ni = 0; ni < 4; ++ni) {
        const int c = moff + wr * 64 + ni * 16 + lf;
        const float sc = oscale[c];
        const float bt = obeta[c];
        const size_t rowb = ((size_t)b * 256 + c) * HW_;
        #pragma unroll
        for (int mi = 0; mi < 4; ++mi) {
            const int l = l0 + wc * 64 + mi * 16 + r4;
            const f32x4 xv = (ni < 2) ? xpre[ni * 4 + mi]
                                      : *(const f32x4*)(x + rowb + l);
            f32x4 o;
            #pragma unroll
            for (int r = 0; r < 4; ++r)
                o[r] = xv[r] + acc[mi][ni][r] * sc + bt;
            *(f32x4*)(out + rowb + l) = o;
        }
    }
}

// ---------------------------------------------------------------------------
extern "C" void kernel_launch(void* const* d_in, const int* in_sizes, int n_in,
                              void* d_out, int out_size, void* d_ws, size_t ws_size,
                              hipStream_t stream) {
    (void)in_sizes; (void)n_in; (void)out_size;
    const float* x     = (const float*)d_in[0];
    const float* w_s   = (const float*)d_in[1];
    const float* b_s   = (const float*)d_in[2];
    const float* g_s   = (const float*)d_in[3];
    const float* bb_s  = (const float*)d_in[4];
    const float* m_s   = (const float*)d_in[5];
    const float* v_s   = (const float*)d_in[6];
    const float* w_p   = (const float*)d_in[7];
    const float* b_p   = (const float*)d_in[8];
    const float* g_p   = (const float*)d_in[9];
    const float* bb_p  = (const float*)d_in[10];
    const float* m_p   = (const float*)d_in[11];
    const float* v_p   = (const float*)d_in[12];
    const float* w_r   = (const float*)d_in[13];
    const float* b_r   = (const float*)d_in[14];
    const float* g_r   = (const float*)d_in[15];
    const float* bb_r  = (const float*)d_in[16];
    const float* m_r   = (const float*)d_in[17];
    const float* v_r   = (const float*)d_in[18];
    const float* g1w1  = (const float*)d_in[19];
    const float* g1b1  = (const float*)d_in[20];
    const float* g1w2  = (const float*)d_in[21];
    const float* g2w1  = (const float*)d_in[22];
    const float* g2b1  = (const float*)d_in[23];
    const float* g2w2  = (const float*)d_in[24];
    const float* fc2w  = (const float*)d_in[25];
    const float* bn_og = (const float*)d_in[26];
    const float* bn_ob = (const float*)d_in[27];
    const float* bn_om = (const float*)d_in[28];
    const float* bn_ov = (const float*)d_in[29];

    char* ws = (char*)d_ws;
    unsigned short* Wcf = (unsigned short*)(ws + 0);         // 131072 B
    float* pscale = (float*)(ws + 131072);
    float* pbeta  = (float*)(ws + 132096);
    float* oscale = (float*)(ws + 133120);
    float* obeta  = (float*)(ws + 134144);
    unsigned short* wbf = (unsigned short*)(ws + 135168);    // 147456 B
    const size_t o_fix = 135168 + 147456;                    // 282624
    const size_t sz_xrt = (size_t)B_ * HW_ * 64 * 2;         // 18,874,368
    const size_t sz_gr  = (size_t)B_ * S_ * N_ * 2;          //    262,144
    const size_t sz_hc  = (size_t)B_ * 256 * 64 * 2;         //    524,288
    const size_t sz_gpb = (size_t)LT_ * B_ * S_ * N_ * 2;    // 37,748,736
    const size_t need_full = o_fix + sz_xrt + sz_gr + sz_hc + sz_gpb;

    unsigned short* xrt  = (unsigned short*)(ws + o_fix);
    unsigned short* gred = (unsigned short*)(ws + o_fix + sz_xrt);
    unsigned short* hc   = (unsigned short*)(ws + o_fix + sz_xrt + sz_gr);
    unsigned short* gpb;
    if (ws_size >= need_full)
        gpb = (unsigned short*)(ws + o_fix + sz_xrt + sz_gr + sz_hc);
    else  // fall back: gpb in d_out (fully consumed by kred before k3 writes out)
        gpb = (unsigned short*)d_out;

    k0_prep<<<544, 256, 0, stream>>>(
        w_s, w_p, w_r,
        b_s, g_s, bb_s, m_s, v_s,
        b_p, g_p, bb_p, m_p, v_p,
        b_r, g_r, bb_r, m_r, v_r,
        bn_og, bn_ob, bn_om, bn_ov,
        g1w1, g1w2, g2w1, g2w2, fc2w,
        Wcf, pscale, pbeta, oscale, obeta, wbf);

    k1_proj<<<dim3(LT_, B_), 256, 0, stream>>>(x, Wcf, pscale, pbeta, xrt, gpb);

    kred<<<64, 256, 0, stream>>>(gpb, gred);

    k_gcn<<<16, 256, 0, stream>>>(gred, wbf, g1b1, g2b1, hc);

    k3_out<<<dim3(72, 2, 16), 256, 0, stream>>>(x, hc, xrt, oscale, obeta, (float*)d_out);
}